// Round 1
// baseline (332.034 us; speedup 1.0000x reference)
//
#include <hip/hip_runtime.h>
#include <hip/hip_bf16.h>
#include <stdint.h>

#define D_MODEL 4096
#define D_BASE  8192
#define K_SUB   1024
#define N_TOK   8192

typedef __attribute__((ext_vector_type(8))) short bf16x8;
typedef __attribute__((ext_vector_type(4))) float f32x4;

__device__ __forceinline__ unsigned short f2bf(float f) {
    union { float f; uint32_t u; } c; c.f = f;
    uint32_t u = c.u;
    uint32_t r = u + 0x7FFFu + ((u >> 16) & 1u);   // round-to-nearest-even
    return (unsigned short)(r >> 16);
}

// Ut[n][k] = bf16(U[k][idx[n]]) ; layout [K_SUB][D_MODEL] (B^T for GEMM1)
__global__ void gather_u_kernel(const float* __restrict__ U, const int* __restrict__ idx,
                                unsigned short* __restrict__ Ut) {
    int t = blockIdx.x * 256 + threadIdx.x;      // K_SUB * D_MODEL threads
    int k = t & (D_MODEL - 1);
    int n = t >> 12;
    int col = idx[n];
    Ut[t] = f2bf(U[(size_t)k * D_BASE + col]);
}

// Vt[d][n] = bf16(V[idx[n]][d]) ; layout [D_MODEL][K_SUB] (B^T for GEMM2)
__global__ void gather_v_kernel(const float* __restrict__ V, const int* __restrict__ idx,
                                unsigned short* __restrict__ Vt) {
    int t = blockIdx.x * 256 + threadIdx.x;      // D_MODEL * K_SUB threads
    int n = t & (K_SUB - 1);
    int d = t >> 10;
    int row = idx[n];
    Vt[t] = f2bf(V[(size_t)row * D_MODEL + d]);
}

// C[M][N] = op(A[M][K]) @ Bt[N][K]^T, bf16 MFMA 16x16x32, 128x128 tile, BK=64.
// A_F32: A is f32 (convert on stage). DO_SILU: apply silu, store bf16; else store f32.
template<int A_F32, int DO_SILU>
__global__ __launch_bounds__(256)
void gemm_bt_kernel(const void* __restrict__ Aptr, const unsigned short* __restrict__ Bt,
                    void* __restrict__ Cptr, int M, int N, int K) {
    __shared__ unsigned short As[128][72];   // +8 pad: 16B-aligned rows, conflict-free reads
    __shared__ unsigned short Bs[128][72];

    const int t = threadIdx.x;
    const int lane = t & 63;
    const int wid = t >> 6;
    const int wr = wid >> 1, wc = wid & 1;
    const int m0 = blockIdx.y * 128, n0 = blockIdx.x * 128;
    const int lr = lane & 15, lk = lane >> 4;

    f32x4 acc[4][4] = {};

    for (int k0 = 0; k0 < K; k0 += 64) {
        // ---- stage A tile (128 x 64) ----
        if (A_F32) {
            const float* A = (const float*)Aptr;
            #pragma unroll
            for (int i = 0; i < 8; ++i) {
                int e = i * 256 + t;                 // float4 units: 16 per row
                int row = e >> 4, c4 = (e & 15) * 4;
                const float4 v = *(const float4*)(A + (size_t)(m0 + row) * K + k0 + c4);
                ushort4 o;
                o.x = f2bf(v.x); o.y = f2bf(v.y); o.z = f2bf(v.z); o.w = f2bf(v.w);
                *(ushort4*)&As[row][c4] = o;
            }
        } else {
            const unsigned short* A = (const unsigned short*)Aptr;
            #pragma unroll
            for (int i = 0; i < 4; ++i) {
                int e = i * 256 + t;                 // ushort8 units: 8 per row
                int row = e >> 3, c8 = (e & 7) * 8;
                *(bf16x8*)&As[row][c8] =
                    *(const bf16x8*)(A + (size_t)(m0 + row) * K + k0 + c8);
            }
        }
        // ---- stage B tile (Bt is [N][K]; Bs[n][k]) ----
        #pragma unroll
        for (int i = 0; i < 4; ++i) {
            int e = i * 256 + t;
            int row = e >> 3, c8 = (e & 7) * 8;
            *(bf16x8*)&Bs[row][c8] =
                *(const bf16x8*)(Bt + (size_t)(n0 + row) * K + k0 + c8);
        }
        __syncthreads();

        #pragma unroll
        for (int ks = 0; ks < 2; ++ks) {
            bf16x8 af[4], bfr[4];
            #pragma unroll
            for (int m = 0; m < 4; ++m)
                af[m] = *(const bf16x8*)&As[wr * 64 + m * 16 + lr][ks * 32 + lk * 8];
            #pragma unroll
            for (int n = 0; n < 4; ++n)
                bfr[n] = *(const bf16x8*)&Bs[wc * 64 + n * 16 + lr][ks * 32 + lk * 8];
            #pragma unroll
            for (int m = 0; m < 4; ++m)
                #pragma unroll
                for (int n = 0; n < 4; ++n)
                    acc[m][n] = __builtin_amdgcn_mfma_f32_16x16x32_bf16(
                        af[m], bfr[n], acc[m][n], 0, 0, 0);
        }
        __syncthreads();
    }

    // ---- epilogue: D row = lk*4 + r (within 16), col = lr ----
    const int orow = m0 + wr * 64;
    const int ocol = n0 + wc * 64;
    if (DO_SILU) {
        unsigned short* C = (unsigned short*)Cptr;
        #pragma unroll
        for (int m = 0; m < 4; ++m)
            #pragma unroll
            for (int n = 0; n < 4; ++n)
                #pragma unroll
                for (int r = 0; r < 4; ++r) {
                    float v = acc[m][n][r];
                    v = v / (1.0f + __expf(-v));     // silu
                    C[(size_t)(orow + m * 16 + lk * 4 + r) * N + (ocol + n * 16 + lr)] = f2bf(v);
                }
    } else {
        float* C = (float*)Cptr;
        #pragma unroll
        for (int m = 0; m < 4; ++m)
            #pragma unroll
            for (int n = 0; n < 4; ++n)
                #pragma unroll
                for (int r = 0; r < 4; ++r)
                    C[(size_t)(orow + m * 16 + lk * 4 + r) * N + (ocol + n * 16 + lr)] =
                        acc[m][n][r];
    }
}

extern "C" void kernel_launch(void* const* d_in, const int* in_sizes, int n_in,
                              void* d_out, int out_size, void* d_ws, size_t ws_size,
                              hipStream_t stream) {
    const float* x   = (const float*)d_in[0];
    const int*   idx = (const int*)d_in[1];
    const float* U   = (const float*)d_in[2];
    const float* V   = (const float*)d_in[3];
    float* out = (float*)d_out;

    unsigned short* Ut = (unsigned short*)d_ws;                 // [K_SUB][D_MODEL] bf16: 8 MB
    unsigned short* Vt = Ut + (size_t)K_SUB * D_MODEL;          // [D_MODEL][K_SUB] bf16: 8 MB
    unsigned short* P  = Vt + (size_t)K_SUB * D_MODEL;          // [N_TOK][K_SUB]  bf16: 16 MB

    // gathers
    gather_u_kernel<<<(K_SUB * D_MODEL) / 256, 256, 0, stream>>>(U, idx, Ut);
    gather_v_kernel<<<(D_MODEL * K_SUB) / 256, 256, 0, stream>>>(V, idx, Vt);

    // GEMM1: P = silu(x @ Usub)  (M=8192, N=1024, K=4096)
    gemm_bt_kernel<1, 1><<<dim3(K_SUB / 128, N_TOK / 128), 256, 0, stream>>>(
        x, Ut, P, N_TOK, K_SUB, D_MODEL);

    // GEMM2: out = P @ Vsub      (M=8192, N=4096, K=1024)
    gemm_bt_kernel<0, 0><<<dim3(D_MODEL / 128, N_TOK / 128), 256, 0, stream>>>(
        P, Vt, out, N_TOK, D_MODEL, K_SUB);
}

// Round 2
// 325.502 us; speedup vs baseline: 1.0201x; 1.0201x over previous
//
#include <hip/hip_runtime.h>
#include <hip/hip_bf16.h>
#include <stdint.h>

#define D_MODEL 4096
#define D_BASE  8192
#define K_SUB   1024
#define N_TOK   8192

typedef __attribute__((ext_vector_type(8))) short bf16x8;
typedef __attribute__((ext_vector_type(4))) float f32x4;

__device__ __forceinline__ unsigned short f2bf(float f) {
    union { float f; uint32_t u; } c; c.f = f;
    uint32_t u = c.u;
    uint32_t r = u + 0x7FFFu + ((u >> 16) & 1u);   // round-to-nearest-even
    return (unsigned short)(r >> 16);
}

__device__ __forceinline__ void gload_lds16(const void* g, void* l) {
    __builtin_amdgcn_global_load_lds(
        (__attribute__((address_space(1))) void*)g,
        (__attribute__((address_space(3))) void*)l, 16, 0, 0);
}

// x (f32) -> xb (bf16), 8 elems/thread
__global__ void convert_x_kernel(const float* __restrict__ x, unsigned short* __restrict__ xb) {
    int t = blockIdx.x * 256 + threadIdx.x;
    const float4* p = (const float4*)x + (size_t)t * 2;
    float4 a = p[0], b = p[1];
    ushort4 lo, hi;
    lo.x = f2bf(a.x); lo.y = f2bf(a.y); lo.z = f2bf(a.z); lo.w = f2bf(a.w);
    hi.x = f2bf(b.x); hi.y = f2bf(b.y); hi.z = f2bf(b.z); hi.w = f2bf(b.w);
    *(ushort4*)(xb + (size_t)t * 8) = lo;
    *(ushort4*)(xb + (size_t)t * 8 + 4) = hi;
}

// Ut[n][k] = bf16(U[k][idx[n]]) ; layout [K_SUB][D_MODEL] (B^T for GEMM1)
__global__ void gather_u_kernel(const float* __restrict__ U, const int* __restrict__ idx,
                                unsigned short* __restrict__ Ut) {
    int t = blockIdx.x * 256 + threadIdx.x;
    int k = t & (D_MODEL - 1);
    int n = t >> 12;
    int col = idx[n];
    Ut[t] = f2bf(U[(size_t)k * D_BASE + col]);
}

// Vt[d][n] = bf16(V[idx[n]][d]) ; layout [D_MODEL][K_SUB] (B^T for GEMM2)
__global__ void gather_v_kernel(const float* __restrict__ V, const int* __restrict__ idx,
                                unsigned short* __restrict__ Vt) {
    int t = blockIdx.x * 256 + threadIdx.x;
    int n = t & (K_SUB - 1);
    int d = t >> 10;
    int row = idx[n];
    Vt[t] = f2bf(V[(size_t)row * D_MODEL + d]);
}

// C[M][N] = A[M][K] @ Bt[N][K]^T, bf16 inputs, MFMA 16x16x32, 128x128 tile, BK=64.
// Linear LDS + global_load_lds width=16 staging (m97 structure).
// DO_SILU: apply silu, store bf16; else store f32.
template<int DO_SILU>
__global__ __launch_bounds__(256)
void gemm_bt_kernel(const unsigned short* __restrict__ A, const unsigned short* __restrict__ Bt,
                    void* __restrict__ Cptr, int M, int N, int K) {
    __shared__ unsigned short As[128 * 64];   // linear: global_load_lds needs contiguous dest
    __shared__ unsigned short Bs[128 * 64];

    const int t = threadIdx.x;
    const int lane = t & 63;
    const int wid = t >> 6;
    const int wr = wid >> 1, wc = wid & 1;
    const int m0 = blockIdx.y * 128, n0 = blockIdx.x * 128;
    const int lr = lane & 15, lk = lane >> 4;

    // staging geometry: issue i covers 8 rows; lane covers row chunk+lane/8, col (lane&7)*8
    const int srow = wid * 8 + (lane >> 3);       // row within 32-row chunk group
    const int scol = (lane & 7) * 8;

    f32x4 acc[4][4] = {};

    for (int k0 = 0; k0 < K; k0 += 64) {
        #pragma unroll
        for (int i = 0; i < 4; ++i) {
            int row = i * 32 + srow;
            gload_lds16(A + (size_t)(m0 + row) * K + k0 + scol,
                        &As[(i * 32 + wid * 8) * 64]);
        }
        #pragma unroll
        for (int i = 0; i < 4; ++i) {
            int row = i * 32 + srow;
            gload_lds16(Bt + (size_t)(n0 + row) * K + k0 + scol,
                        &Bs[(i * 32 + wid * 8) * 64]);
        }
        __syncthreads();

        #pragma unroll
        for (int ks = 0; ks < 2; ++ks) {
            bf16x8 af[4], bfr[4];
            #pragma unroll
            for (int m = 0; m < 4; ++m)
                af[m] = *(const bf16x8*)&As[(wr * 64 + m * 16 + lr) * 64 + ks * 32 + lk * 8];
            #pragma unroll
            for (int n = 0; n < 4; ++n)
                bfr[n] = *(const bf16x8*)&Bs[(wc * 64 + n * 16 + lr) * 64 + ks * 32 + lk * 8];
            #pragma unroll
            for (int m = 0; m < 4; ++m)
                #pragma unroll
                for (int n = 0; n < 4; ++n)
                    acc[m][n] = __builtin_amdgcn_mfma_f32_16x16x32_bf16(
                        af[m], bfr[n], acc[m][n], 0, 0, 0);
        }
        __syncthreads();
    }

    const int orow = m0 + wr * 64;
    const int ocol = n0 + wc * 64;
    if (DO_SILU) {
        unsigned short* C = (unsigned short*)Cptr;
        #pragma unroll
        for (int m = 0; m < 4; ++m)
            #pragma unroll
            for (int n = 0; n < 4; ++n)
                #pragma unroll
                for (int r = 0; r < 4; ++r) {
                    float v = acc[m][n][r];
                    v = v / (1.0f + __expf(-v));     // silu
                    C[(size_t)(orow + m * 16 + lk * 4 + r) * N + (ocol + n * 16 + lr)] = f2bf(v);
                }
    } else {
        float* C = (float*)Cptr;
        #pragma unroll
        for (int m = 0; m < 4; ++m)
            #pragma unroll
            for (int n = 0; n < 4; ++n)
                #pragma unroll
                for (int r = 0; r < 4; ++r)
                    C[(size_t)(orow + m * 16 + lk * 4 + r) * N + (ocol + n * 16 + lr)] =
                        acc[m][n][r];
    }
}

extern "C" void kernel_launch(void* const* d_in, const int* in_sizes, int n_in,
                              void* d_out, int out_size, void* d_ws, size_t ws_size,
                              hipStream_t stream) {
    const float* x   = (const float*)d_in[0];
    const int*   idx = (const int*)d_in[1];
    const float* U   = (const float*)d_in[2];
    const float* V   = (const float*)d_in[3];
    float* out = (float*)d_out;

    unsigned short* Ut = (unsigned short*)d_ws;                 // [K_SUB][D_MODEL] bf16: 8 MB
    unsigned short* Vt = Ut + (size_t)K_SUB * D_MODEL;          // [D_MODEL][K_SUB] bf16: 8 MB
    unsigned short* P  = Vt + (size_t)K_SUB * D_MODEL;          // [N_TOK][K_SUB]  bf16: 16 MB
    // xb lives in d_out (64 MiB of the 128 MiB output buffer); GEMM1 finishes
    // reading it before GEMM2 overwrites d_out. Deterministic every call.
    unsigned short* xb = (unsigned short*)d_out;                // [N_TOK][D_MODEL] bf16

    convert_x_kernel<<<(N_TOK * D_MODEL) / (256 * 8), 256, 0, stream>>>(x, xb);
    gather_u_kernel<<<(K_SUB * D_MODEL) / 256, 256, 0, stream>>>(U, idx, Ut);
    gather_v_kernel<<<(D_MODEL * K_SUB) / 256, 256, 0, stream>>>(V, idx, Vt);

    // GEMM1: P = silu(xb @ Usub)  (M=8192, N=1024, K=4096)
    gemm_bt_kernel<1><<<dim3(K_SUB / 128, N_TOK / 128), 256, 0, stream>>>(
        xb, Ut, P, N_TOK, K_SUB, D_MODEL);

    // GEMM2: out = P @ Vsub       (M=8192, N=4096, K=1024)
    gemm_bt_kernel<0><<<dim3(D_MODEL / 128, N_TOK / 128), 256, 0, stream>>>(
        P, Vt, out, N_TOK, D_MODEL, K_SUB);
}

// Round 3
// 276.991 us; speedup vs baseline: 1.1987x; 1.1751x over previous
//
#include <hip/hip_runtime.h>
#include <hip/hip_bf16.h>
#include <stdint.h>

#define D_MODEL 4096
#define D_BASE  8192
#define K_SUB   1024
#define N_TOK   8192

typedef __attribute__((ext_vector_type(8))) short bf16x8;
typedef __attribute__((ext_vector_type(4))) float f32x4;

__device__ __forceinline__ unsigned short f2bf(float f) {
    union { float f; uint32_t u; } c; c.f = f;
    uint32_t u = c.u;
    uint32_t r = u + 0x7FFFu + ((u >> 16) & 1u);   // round-to-nearest-even
    return (unsigned short)(r >> 16);
}

__device__ __forceinline__ void gload_lds16(const void* g, void* l) {
    __builtin_amdgcn_global_load_lds(
        (__attribute__((address_space(1))) void*)g,
        (__attribute__((address_space(3))) void*)l, 16, 0, 0);
}

// x (f32) -> xb (bf16), 8 elems/thread
__global__ void convert_x_kernel(const float* __restrict__ x, unsigned short* __restrict__ xb) {
    int t = blockIdx.x * 256 + threadIdx.x;
    const float4* p = (const float4*)x + (size_t)t * 2;
    float4 a = p[0], b = p[1];
    ushort4 lo, hi;
    lo.x = f2bf(a.x); lo.y = f2bf(a.y); lo.z = f2bf(a.z); lo.w = f2bf(a.w);
    hi.x = f2bf(b.x); hi.y = f2bf(b.y); hi.z = f2bf(b.z); hi.w = f2bf(b.w);
    *(ushort4*)(xb + (size_t)t * 8) = lo;
    *(ushort4*)(xb + (size_t)t * 8 + 4) = hi;
}

// Ut[n][k] = bf16(U[k][idx[n]]) ; layout [K_SUB][D_MODEL]
__global__ void gather_u_kernel(const float* __restrict__ U, const int* __restrict__ idx,
                                unsigned short* __restrict__ Ut) {
    int t = blockIdx.x * 256 + threadIdx.x;
    int k = t & (D_MODEL - 1);
    int n = t >> 12;
    int col = idx[n];
    Ut[t] = f2bf(U[(size_t)k * D_BASE + col]);
}

// Vt[d][n] = bf16(V[idx[n]][d]) ; layout [D_MODEL][K_SUB]
__global__ void gather_v_kernel(const float* __restrict__ V, const int* __restrict__ idx,
                                unsigned short* __restrict__ Vt) {
    int t = blockIdx.x * 256 + threadIdx.x;
    int n = t & (K_SUB - 1);
    int d = t >> 10;
    int row = idx[n];
    Vt[t] = f2bf(V[(size_t)row * D_MODEL + d]);
}

template<int FM, int FN, int MH, int NH>
__device__ __forceinline__ void mma_q(f32x4 (&acc)[2 * FM][2 * FN],
                                      const bf16x8 (&af)[FM][2], const bf16x8 (&bf)[FN][2]) {
    __builtin_amdgcn_s_setprio(1);
    #pragma unroll
    for (int m = 0; m < FM; ++m)
        #pragma unroll
        for (int n = 0; n < FN; ++n)
            #pragma unroll
            for (int ks = 0; ks < 2; ++ks)
                acc[MH * FM + m][NH * FN + n] = __builtin_amdgcn_mfma_f32_16x16x32_bf16(
                    af[m][ks], bf[n][ks], acc[MH * FM + m][NH * FN + n], 0, 0, 0);
    __builtin_amdgcn_s_setprio(0);
}

#define PHASE_MID() do { __builtin_amdgcn_sched_barrier(0); __builtin_amdgcn_s_barrier(); \
    asm volatile("s_waitcnt lgkmcnt(0)" ::: "memory"); __builtin_amdgcn_sched_barrier(0); } while (0)
#define PHASE_END() do { __builtin_amdgcn_sched_barrier(0); __builtin_amdgcn_s_barrier(); } while (0)

// C[M][N] = A[M][K] @ Bt[N][K]^T, bf16 in, 8-phase schedule (T2+T3+T4+T5).
// 8 waves: wave (wr,wc) owns 2x2 scattered 64xQN blocks: rows {mh*BM/2 + wr*64},
// cols {nh*BN/2 + wc*QN}. Per K-tile 4 phases, quadrant (mh,nh) = p{00,01,10,11}.
// Half-tile slot last-LDS-read phases: A0:p0 B0:p0 B1:p1 A1:p2 -> safe overwrite
// issues (tile kt+2, same buf): A0@p1 B1@p2 A1@p3; B0(kt+1)@p0 (other buf).
// Steady vmcnt(4+LB) at p3-end leaves only {A0,B1,A1}(kt+2) in flight.
template<int BM, int BN, int QN, int DO_SILU>
__global__ __launch_bounds__(512, 2)
void gemm8p(const unsigned short* __restrict__ A, const unsigned short* __restrict__ Bt,
            void* __restrict__ Cptr, int M, int N, int K) {
    constexpr int QM = 64;
    constexpr int FM = QM / 16;          // 4
    constexpr int FN = QN / 16;          // 2 (BN=256) or 1 (BN=128)
    constexpr int AHALF = (BM / 2) * 64; // ushorts per A staging half
    constexpr int BHALF = (BN / 2) * 64;
    constexpr int BUFSZ = (BM + BN) * 64;
    constexpr int LB = BN / 128;         // gloads/thread per B half

    __shared__ __align__(16) unsigned short lds[2 * BUFSZ];

    const int t = threadIdx.x, lane = t & 63, w = t >> 6;
    const int wr = w >> 2, wc = w & 3;
    const int lr = lane & 15, lk = lane >> 4;
    const int m0 = blockIdx.y * BM, n0 = blockIdx.x * BN;

    // read-side swizzle: granule (ks*4+lk) ^ (row&7), row&7 == lr&7 (ushort offsets)
    const int cswz0 = ((lk ^ (lr & 7)) * 8);
    const int cswz1 = (((4 + lk) ^ (lr & 7)) * 8);
    // stage-side: lane l covers lds granule (l&7) of row (..+l>>3); source granule pre-swizzled
    const int srow = lane >> 3;
    const int scol = ((lane & 7) ^ srow) * 8;

    auto stage_A = [&](int kt, int mh) {
        const unsigned short* src = A + (size_t)(m0 + mh * (BM / 2)) * K + kt * 64;
        unsigned short* dst = &lds[(kt & 1) * BUFSZ + mh * AHALF];
        #pragma unroll
        for (int i = 0; i < BM / 128; ++i) {
            int c = i * 8 + w;
            gload_lds16(src + (size_t)(c * 8 + srow) * K + scol, dst + c * 512);
        }
    };
    auto stage_B = [&](int kt, int nh) {
        const unsigned short* src = Bt + (size_t)(n0 + nh * (BN / 2)) * K + kt * 64;
        unsigned short* dst = &lds[(kt & 1) * BUFSZ + BM * 64 + nh * BHALF];
        #pragma unroll
        for (int i = 0; i < BN / 128; ++i) {
            int c = i * 8 + w;
            gload_lds16(src + (size_t)(c * 8 + srow) * K + scol, dst + c * 512);
        }
    };
    auto read_A = [&](int kt, int mh, bf16x8 (&af)[FM][2]) {
        const unsigned short* base = &lds[(kt & 1) * BUFSZ + mh * AHALF];
        #pragma unroll
        for (int m = 0; m < FM; ++m) {
            int rw = wr * QM + m * 16 + lr;
            af[m][0] = *(const bf16x8*)(base + rw * 64 + cswz0);
            af[m][1] = *(const bf16x8*)(base + rw * 64 + cswz1);
        }
    };
    auto read_B = [&](int kt, int nh, bf16x8 (&bf)[FN][2]) {
        const unsigned short* base = &lds[(kt & 1) * BUFSZ + BM * 64 + nh * BHALF];
        #pragma unroll
        for (int n = 0; n < FN; ++n) {
            int rw = wc * QN + n * 16 + lr;
            bf[n][0] = *(const bf16x8*)(base + rw * 64 + cswz0);
            bf[n][1] = *(const bf16x8*)(base + rw * 64 + cswz1);
        }
    };

    f32x4 acc[2 * FM][2 * FN] = {};
    const int NT = K / 64;

    // prologue: tile0 all 4 halves + tile1 {A0,B1,A1}; wait leaves tile1's 3 in flight
    stage_A(0, 0); stage_B(0, 0); stage_B(0, 1); stage_A(0, 1);
    stage_A(1, 0); stage_B(1, 1); stage_A(1, 1);
    __builtin_amdgcn_sched_barrier(0);
    if constexpr (LB == 2) asm volatile("s_waitcnt vmcnt(6)" ::: "memory");
    else                   asm volatile("s_waitcnt vmcnt(5)" ::: "memory");
    __builtin_amdgcn_s_barrier();
    __builtin_amdgcn_sched_barrier(0);

    for (int kt = 0; kt < NT; ++kt) {
        bf16x8 af[FM][2], bf0[FN][2], bf1[FN][2];
        // ---- p0: quadrant (0,0) ----
        read_A(kt, 0, af); read_B(kt, 0, bf0);
        if (kt + 1 < NT) stage_B(kt + 1, 0);
        PHASE_MID();
        mma_q<FM, FN, 0, 0>(acc, af, bf0);
        PHASE_END();
        // ---- p1: quadrant (0,1) ----
        read_B(kt, 1, bf1);
        if (kt + 2 < NT) stage_A(kt + 2, 0);
        PHASE_MID();
        mma_q<FM, FN, 0, 1>(acc, af, bf1);
        PHASE_END();
        // ---- p2: quadrant (1,0) ----
        read_A(kt, 1, af);          // af dead after p1 -> reuse regs
        if (kt + 2 < NT) stage_B(kt + 2, 1);
        PHASE_MID();
        mma_q<FM, FN, 1, 0>(acc, af, bf0);
        PHASE_END();
        // ---- p3: quadrant (1,1) ----
        if (kt + 2 < NT) stage_A(kt + 2, 1);
        PHASE_MID();
        mma_q<FM, FN, 1, 1>(acc, af, bf1);
        __builtin_amdgcn_sched_barrier(0);
        if (kt < NT - 2) {
            if constexpr (LB == 2) asm volatile("s_waitcnt vmcnt(6)" ::: "memory");
            else                   asm volatile("s_waitcnt vmcnt(5)" ::: "memory");
        } else if (kt == NT - 2) {
            asm volatile("s_waitcnt vmcnt(0)" ::: "memory");
        }
        PHASE_END();
    }

    // ---- epilogue ----
    #pragma unroll
    for (int mh = 0; mh < 2; ++mh)
        #pragma unroll
        for (int nh = 0; nh < 2; ++nh)
            #pragma unroll
            for (int m = 0; m < FM; ++m)
                #pragma unroll
                for (int n = 0; n < FN; ++n)
                    #pragma unroll
                    for (int r = 0; r < 4; ++r) {
                        int row = m0 + mh * (BM / 2) + wr * QM + m * 16 + lk * 4 + r;
                        int col = n0 + nh * (BN / 2) + wc * QN + n * 16 + lr;
                        float v = acc[mh * FM + m][nh * FN + n][r];
                        if (DO_SILU) {
                            v = v / (1.0f + __expf(-v));
                            ((unsigned short*)Cptr)[(size_t)row * N + col] = f2bf(v);
                        } else {
                            ((float*)Cptr)[(size_t)row * N + col] = v;
                        }
                    }
}

extern "C" void kernel_launch(void* const* d_in, const int* in_sizes, int n_in,
                              void* d_out, int out_size, void* d_ws, size_t ws_size,
                              hipStream_t stream) {
    const float* x   = (const float*)d_in[0];
    const int*   idx = (const int*)d_in[1];
    const float* U   = (const float*)d_in[2];
    const float* V   = (const float*)d_in[3];
    float* out = (float*)d_out;

    unsigned short* Ut = (unsigned short*)d_ws;                 // [K_SUB][D_MODEL] bf16
    unsigned short* Vt = Ut + (size_t)K_SUB * D_MODEL;          // [D_MODEL][K_SUB] bf16
    unsigned short* P  = Vt + (size_t)K_SUB * D_MODEL;          // [N_TOK][K_SUB]  bf16
    unsigned short* xb = (unsigned short*)d_out;                // [N_TOK][D_MODEL] bf16 (temp in d_out)

    convert_x_kernel<<<(N_TOK * D_MODEL) / (256 * 8), 256, 0, stream>>>(x, xb);
    gather_u_kernel<<<(K_SUB * D_MODEL) / 256, 256, 0, stream>>>(U, idx, Ut);
    gather_v_kernel<<<(D_MODEL * K_SUB) / 256, 256, 0, stream>>>(V, idx, Vt);

    // GEMM1: P = silu(xb @ Usub)  M=8192 N=1024 K=4096; BM=256 BN=128 -> 256 blocks
    gemm8p<256, 128, 16, 1><<<dim3(K_SUB / 128, N_TOK / 256), 512, 0, stream>>>(
        xb, Ut, P, N_TOK, K_SUB, D_MODEL);

    // GEMM2: out = P @ Vsub       M=8192 N=4096 K=1024; 256x256 -> 512 blocks
    gemm8p<256, 256, 32, 0><<<dim3(D_MODEL / 256, N_TOK / 256), 512, 0, stream>>>(
        P, Vt, out, N_TOK, D_MODEL, K_SUB);
}

// Round 4
// 244.550 us; speedup vs baseline: 1.3577x; 1.1327x over previous
//
#include <hip/hip_runtime.h>
#include <hip/hip_bf16.h>
#include <stdint.h>

#define D_MODEL 4096
#define D_BASE  8192
#define K_SUB   1024
#define N_TOK   8192

typedef __attribute__((ext_vector_type(8))) short bf16x8;
typedef __attribute__((ext_vector_type(4))) float f32x4;

__device__ __forceinline__ unsigned short f2bf(float f) {
    union { float f; uint32_t u; } c; c.f = f;
    uint32_t u = c.u;
    uint32_t r = u + 0x7FFFu + ((u >> 16) & 1u);   // round-to-nearest-even
    return (unsigned short)(r >> 16);
}

__device__ __forceinline__ void gload_lds16(const void* g, void* l) {
    __builtin_amdgcn_global_load_lds(
        (__attribute__((address_space(1))) void*)g,
        (__attribute__((address_space(3))) void*)l, 16, 0, 0);
}

#define VMCNT(N) do { __builtin_amdgcn_sched_barrier(0); \
    asm volatile("s_waitcnt vmcnt(" #N ")" ::: "memory"); } while (0)
#define PHASE_MID() do { __builtin_amdgcn_sched_barrier(0); __builtin_amdgcn_s_barrier(); \
    asm volatile("s_waitcnt lgkmcnt(0)" ::: "memory"); __builtin_amdgcn_sched_barrier(0); } while (0)
#define PHASE_END() do { __builtin_amdgcn_sched_barrier(0); __builtin_amdgcn_s_barrier(); } while (0)

// x (f32) -> xb (bf16), 8 elems/thread
__global__ void convert_x_kernel(const float* __restrict__ x, unsigned short* __restrict__ xb) {
    int t = blockIdx.x * 256 + threadIdx.x;
    const float4* p = (const float4*)x + (size_t)t * 2;
    float4 a = p[0], b = p[1];
    ushort4 lo, hi;
    lo.x = f2bf(a.x); lo.y = f2bf(a.y); lo.z = f2bf(a.z); lo.w = f2bf(a.w);
    hi.x = f2bf(b.x); hi.y = f2bf(b.y); hi.z = f2bf(b.z); hi.w = f2bf(b.w);
    *(ushort4*)(xb + (size_t)t * 8) = lo;
    *(ushort4*)(xb + (size_t)t * 8 + 4) = hi;
}

// Ut[n][k] = bf16(U[k][idx[n]]), via 64x64 LDS transpose tile.
// Reads: 64 gathered dwords within ONE row of U per wave (row-local).
// Writes: 128B contiguous runs. LDS stride 66 ushorts -> 2-way max (free).
__global__ __launch_bounds__(256) void gather_u_t(const float* __restrict__ U,
                                                  const int* __restrict__ idx,
                                                  unsigned short* __restrict__ Ut) {
    __shared__ unsigned short tile[64][66];
    __shared__ int lidx[64];
    const int t = threadIdx.x;
    const int n0 = (blockIdx.x & 15) * 64;
    const int k0 = (blockIdx.x >> 4) * 64;
    if (t < 64) lidx[t] = idx[n0 + t];
    __syncthreads();
    const int c = t & 63, r4 = t >> 6;
    #pragma unroll
    for (int p = 0; p < 16; ++p) {
        int kr = p * 4 + r4;
        tile[c][kr] = f2bf(U[(size_t)(k0 + kr) * D_BASE + lidx[c]]);
    }
    __syncthreads();
    #pragma unroll
    for (int p = 0; p < 16; ++p) {
        int nr = p * 4 + r4;
        Ut[(size_t)(n0 + nr) * D_MODEL + k0 + c] = tile[nr][c];
    }
}

// Vt[d][n] = bf16(V[idx[n]][d]), via 64x64 LDS transpose tile.
// Reads: 256B coalesced row segments. Writes: 128B contiguous runs.
__global__ __launch_bounds__(256) void gather_v_t(const float* __restrict__ V,
                                                  const int* __restrict__ idx,
                                                  unsigned short* __restrict__ Vt) {
    __shared__ unsigned short tile[64][66];
    __shared__ int lidx[64];
    const int t = threadIdx.x;
    const int n0 = (blockIdx.x & 15) * 64;
    const int d0 = (blockIdx.x >> 4) * 64;
    if (t < 64) lidx[t] = idx[n0 + t];
    __syncthreads();
    const int c = t & 63, r4 = t >> 6;
    #pragma unroll
    for (int p = 0; p < 16; ++p) {
        int nr = p * 4 + r4;
        tile[nr][c] = f2bf(V[(size_t)lidx[nr] * D_MODEL + d0 + c]);
    }
    __syncthreads();
    #pragma unroll
    for (int p = 0; p < 16; ++p) {
        int dr = p * 4 + r4;
        Vt[(size_t)(d0 + dr) * K_SUB + n0 + c] = tile[c][dr];
    }
}

// ---------------- GEMM1: P = silu(xb @ Usub), M=8192 N=1024 K=4096 ----------------
// BM=256 BN=128 BK=64. 8 waves (2M x 4N). 4 phases per 2 K-tiles; each phase =
// one A-half (128 rows) x full BN x K=64 -> 16 MFMA/wave/phase.
// Slots per buffer: A0(128x64) A1(128x64) B(128x64); double-buffered by tile parity.
// Stage schedule (iter tiles T,T+1): p0: A1[T+1] | p1: B[T+2] | p2: A0[T+2],A1[T+2]
// | p3: B[T+3],A0[T+3]. Every stage >=1 barrier after the slot's last ds_read.
// Steady waits p0/p1/p2/p3 = vmcnt 6/4/6/6 (2 loads per half); last iter 6/2/0/-.
template<int MH>
__device__ __forceinline__ void mma_h(f32x4 (&acc)[8][2],
                                      const bf16x8 (&af)[4][2], const bf16x8 (&bfr)[2][2]) {
    __builtin_amdgcn_s_setprio(1);
    #pragma unroll
    for (int m = 0; m < 4; ++m)
        #pragma unroll
        for (int n = 0; n < 2; ++n)
            #pragma unroll
            for (int ks = 0; ks < 2; ++ks)
                acc[MH * 4 + m][n] = __builtin_amdgcn_mfma_f32_16x16x32_bf16(
                    af[m][ks], bfr[n][ks], acc[MH * 4 + m][n], 0, 0, 0);
    __builtin_amdgcn_s_setprio(0);
}

__global__ __launch_bounds__(512, 2)
void gemm1_8p(const unsigned short* __restrict__ A, const unsigned short* __restrict__ Bt,
              unsigned short* __restrict__ C) {
    constexpr int K = D_MODEL, N = K_SUB, NT = K / 64;   // NT=64
    __shared__ __align__(16) unsigned short lds[49152]; // 96 KB: 2 x (A:16K + B:8K ushorts)

    const int t = threadIdx.x, lane = t & 63, w = t >> 6;
    const int wr = w >> 2, wc = w & 3;
    const int lr = lane & 15, lk = lane >> 4;

    // T1 XCD swizzle: 256 blocks, chunk of 32 per XCD = 4 rows x 8 cols
    const int f = blockIdx.x;
    const int g = (f & 7) * 32 + (f >> 3);
    const int m0 = (g >> 3) * 256, n0 = (g & 7) * 128;

    const int cswz0 = ((lk ^ (lr & 7)) * 8);
    const int cswz1 = (((4 + lk) ^ (lr & 7)) * 8);
    const int srow = lane >> 3;
    const int scol = ((lane & 7) ^ srow) * 8;

    auto stage_A = [&](int kt, int mh) {
        const unsigned short* src = A + (size_t)(m0 + mh * 128) * K + kt * 64;
        unsigned short* dst = &lds[(kt & 1) * 24576 + mh * 8192];
        #pragma unroll
        for (int i = 0; i < 2; ++i) {
            int c = i * 8 + w;
            gload_lds16(src + (size_t)(c * 8 + srow) * K + scol, dst + c * 512);
        }
    };
    auto stage_B = [&](int kt) {
        const unsigned short* src = Bt + (size_t)n0 * K + kt * 64;
        unsigned short* dst = &lds[(kt & 1) * 24576 + 16384];
        #pragma unroll
        for (int i = 0; i < 2; ++i) {
            int c = i * 8 + w;
            gload_lds16(src + (size_t)(c * 8 + srow) * K + scol, dst + c * 512);
        }
    };
    auto read_A = [&](int kt, int mh, bf16x8 (&af)[4][2]) {
        const unsigned short* base = &lds[(kt & 1) * 24576 + mh * 8192];
        #pragma unroll
        for (int m = 0; m < 4; ++m) {
            int rw = wr * 64 + m * 16 + lr;
            af[m][0] = *(const bf16x8*)(base + rw * 64 + cswz0);
            af[m][1] = *(const bf16x8*)(base + rw * 64 + cswz1);
        }
    };
    auto read_B = [&](int kt, bf16x8 (&bfr)[2][2]) {
        const unsigned short* base = &lds[(kt & 1) * 24576 + 16384];
        #pragma unroll
        for (int n = 0; n < 2; ++n) {
            int rw = wc * 32 + n * 16 + lr;
            bfr[n][0] = *(const bf16x8*)(base + rw * 64 + cswz0);
            bfr[n][1] = *(const bf16x8*)(base + rw * 64 + cswz1);
        }
    };

    f32x4 acc[8][2] = {};

    // prologue: B[0],A0[0],A1[0],B[1],A0[1]; drain through A0[0] -> vmcnt(6)
    stage_B(0); stage_A(0, 0); stage_A(0, 1); stage_B(1); stage_A(1, 0);
    VMCNT(6);
    __builtin_amdgcn_s_barrier();
    __builtin_amdgcn_sched_barrier(0);

    for (int kt = 0; kt < NT; kt += 2) {
        const bool more = (kt + 2 < NT);
        bf16x8 bf0[2][2], bf1[2][2];
        {   // p0: tile kt, A-half 0
            bf16x8 af[4][2];
            read_A(kt, 0, af); read_B(kt, bf0);
            stage_A(kt + 1, 1);
            PHASE_MID();
            mma_h<0>(acc, af, bf0);
            VMCNT(6);
            PHASE_END();
        }
        {   // p1: tile kt, A-half 1
            bf16x8 af[4][2];
            read_A(kt, 1, af);
            if (more) stage_B(kt + 2);
            PHASE_MID();
            mma_h<1>(acc, af, bf0);
            if (more) { VMCNT(4); } else { VMCNT(2); }
            PHASE_END();
        }
        {   // p2: tile kt+1, A-half 0
            bf16x8 af[4][2];
            read_A(kt + 1, 0, af); read_B(kt + 1, bf1);
            if (more) { stage_A(kt + 2, 0); stage_A(kt + 2, 1); }
            PHASE_MID();
            mma_h<0>(acc, af, bf1);
            if (more) { VMCNT(6); } else { VMCNT(0); }
            PHASE_END();
        }
        {   // p3: tile kt+1, A-half 1
            bf16x8 af[4][2];
            read_A(kt + 1, 1, af);
            if (kt + 3 < NT) { stage_B(kt + 3); stage_A(kt + 3, 0); }
            PHASE_MID();
            mma_h<1>(acc, af, bf1);
            if (more) VMCNT(6);
            PHASE_END();
        }
    }

    #pragma unroll
    for (int mh = 0; mh < 2; ++mh)
        #pragma unroll
        for (int m = 0; m < 4; ++m)
            #pragma unroll
            for (int n = 0; n < 2; ++n)
                #pragma unroll
                for (int r = 0; r < 4; ++r) {
                    int row = m0 + mh * 128 + wr * 64 + m * 16 + lk * 4 + r;
                    int col = n0 + wc * 32 + n * 16 + lr;
                    float v = acc[mh * 4 + m][n][r];
                    v = v / (1.0f + __expf(-v));
                    C[(size_t)row * N + col] = f2bf(v);
                }
}

// ---------------- GEMM2: out = P @ Vsub, M=8192 N=4096 K=1024 ----------------
// Round-3 proven 4-quadrant schedule (16 MFMA/phase), 256x256, + T1 swizzle.
__global__ __launch_bounds__(512, 2)
void gemm2_8p(const unsigned short* __restrict__ A, const unsigned short* __restrict__ Bt,
              float* __restrict__ C) {
    constexpr int K = K_SUB, N = D_MODEL, NT = K / 64;   // NT=16
    constexpr int BUFSZ = 32768;                          // (256+256)*64 ushorts
    __shared__ __align__(16) unsigned short lds[2 * BUFSZ];   // 128 KB

    const int t = threadIdx.x, lane = t & 63, w = t >> 6;
    const int wr = w >> 2, wc = w & 3;
    const int lr = lane & 15, lk = lane >> 4;

    // T1 XCD swizzle: 512 blocks, chunk of 64 per XCD = 4 rows x 16 cols
    const int f = blockIdx.x;
    const int g = (f & 7) * 64 + (f >> 3);
    const int m0 = (g >> 4) * 256, n0 = (g & 15) * 256;

    const int cswz0 = ((lk ^ (lr & 7)) * 8);
    const int cswz1 = (((4 + lk) ^ (lr & 7)) * 8);
    const int srow = lane >> 3;
    const int scol = ((lane & 7) ^ srow) * 8;

    auto stage_A = [&](int kt, int mh) {
        const unsigned short* src = A + (size_t)(m0 + mh * 128) * K + kt * 64;
        unsigned short* dst = &lds[(kt & 1) * BUFSZ + mh * 8192];
        #pragma unroll
        for (int i = 0; i < 2; ++i) {
            int c = i * 8 + w;
            gload_lds16(src + (size_t)(c * 8 + srow) * K + scol, dst + c * 512);
        }
    };
    auto stage_B = [&](int kt, int nh) {
        const unsigned short* src = Bt + (size_t)(n0 + nh * 128) * K + kt * 64;
        unsigned short* dst = &lds[(kt & 1) * BUFSZ + 16384 + nh * 8192];
        #pragma unroll
        for (int i = 0; i < 2; ++i) {
            int c = i * 8 + w;
            gload_lds16(src + (size_t)(c * 8 + srow) * K + scol, dst + c * 512);
        }
    };
    auto read_A = [&](int kt, int mh, bf16x8 (&af)[4][2]) {
        const unsigned short* base = &lds[(kt & 1) * BUFSZ + mh * 8192];
        #pragma unroll
        for (int m = 0; m < 4; ++m) {
            int rw = wr * 64 + m * 16 + lr;
            af[m][0] = *(const bf16x8*)(base + rw * 64 + cswz0);
            af[m][1] = *(const bf16x8*)(base + rw * 64 + cswz1);
        }
    };
    auto read_B = [&](int kt, int nh, bf16x8 (&bfr)[2][2]) {
        const unsigned short* base = &lds[(kt & 1) * BUFSZ + 16384 + nh * 8192];
        #pragma unroll
        for (int n = 0; n < 2; ++n) {
            int rw = wc * 32 + n * 16 + lr;
            bfr[n][0] = *(const bf16x8*)(base + rw * 64 + cswz0);
            bfr[n][1] = *(const bf16x8*)(base + rw * 64 + cswz1);
        }
    };

    f32x4 acc[8][4] = {};

    // prologue: tile0 all 4 halves + tile1 {A0,B1,A1}; vmcnt leaves tile1's 3 (6 loads)
    stage_A(0, 0); stage_B(0, 0); stage_B(0, 1); stage_A(0, 1);
    stage_A(1, 0); stage_B(1, 1); stage_A(1, 1);
    VMCNT(6);
    __builtin_amdgcn_s_barrier();
    __builtin_amdgcn_sched_barrier(0);

    for (int kt = 0; kt < NT; ++kt) {
        bf16x8 af[4][2], bf0[2][2], bf1[2][2];
        {   // p0: quadrant (0,0)
            read_A(kt, 0, af); read_B(kt, 0, bf0);
            if (kt + 1 < NT) stage_B(kt + 1, 0);
            PHASE_MID();
            __builtin_amdgcn_s_setprio(1);
            #pragma unroll
            for (int m = 0; m < 4; ++m)
                #pragma unroll
                for (int n = 0; n < 2; ++n)
                    #pragma unroll
                    for (int ks = 0; ks < 2; ++ks)
                        acc[m][n] = __builtin_amdgcn_mfma_f32_16x16x32_bf16(
                            af[m][ks], bf0[n][ks], acc[m][n], 0, 0, 0);
            __builtin_amdgcn_s_setprio(0);
            PHASE_END();
        }
        {   // p1: quadrant (0,1)
            read_B(kt, 1, bf1);
            if (kt + 2 < NT) stage_A(kt + 2, 0);
            PHASE_MID();
            __builtin_amdgcn_s_setprio(1);
            #pragma unroll
            for (int m = 0; m < 4; ++m)
                #pragma unroll
                for (int n = 0; n < 2; ++n)
                    #pragma unroll
                    for (int ks = 0; ks < 2; ++ks)
                        acc[m][2 + n] = __builtin_amdgcn_mfma_f32_16x16x32_bf16(
                            af[m][ks], bf1[n][ks], acc[m][2 + n], 0, 0, 0);
            __builtin_amdgcn_s_setprio(0);
            PHASE_END();
        }
        {   // p2: quadrant (1,0)
            read_A(kt, 1, af);
            if (kt + 2 < NT) stage_B(kt + 2, 1);
            PHASE_MID();
            __builtin_amdgcn_s_setprio(1);
            #pragma unroll
            for (int m = 0; m < 4; ++m)
                #pragma unroll
                for (int n = 0; n < 2; ++n)
                    #pragma unroll
                    for (int ks = 0; ks < 2; ++ks)
                        acc[4 + m][n] = __builtin_amdgcn_mfma_f32_16x16x32_bf16(
                            af[m][ks], bf0[n][ks], acc[4 + m][n], 0, 0, 0);
            __builtin_amdgcn_s_setprio(0);
            PHASE_END();
        }
        {   // p3: quadrant (1,1)
            if (kt + 2 < NT) stage_A(kt + 2, 1);
            PHASE_MID();
            __builtin_amdgcn_s_setprio(1);
            #pragma unroll
            for (int m = 0; m < 4; ++m)
                #pragma unroll
                for (int n = 0; n < 2; ++n)
                    #pragma unroll
                    for (int ks = 0; ks < 2; ++ks)
                        acc[4 + m][2 + n] = __builtin_amdgcn_mfma_f32_16x16x32_bf16(
                            af[m][ks], bf1[n][ks], acc[4 + m][2 + n], 0, 0, 0);
            __builtin_amdgcn_s_setprio(0);
            __builtin_amdgcn_sched_barrier(0);
            if (kt < NT - 2) { VMCNT(6); }
            else if (kt == NT - 2) { VMCNT(0); }
            PHASE_END();
        }
    }

    #pragma unroll
    for (int mh = 0; mh < 2; ++mh)
        #pragma unroll
        for (int nh = 0; nh < 2; ++nh)
            #pragma unroll
            for (int m = 0; m < 4; ++m)
                #pragma unroll
                for (int n = 0; n < 2; ++n)
                    #pragma unroll
                    for (int r = 0; r < 4; ++r) {
                        int row = m0 + mh * 128 + wr * 64 + m * 16 + lk * 4 + r;
                        int col = n0 + nh * 128 + wc * 32 + n * 16 + lr;
                        C[(size_t)row * N + col] = acc[mh * 4 + m][nh * 2 + n][r];
                    }
}

extern "C" void kernel_launch(void* const* d_in, const int* in_sizes, int n_in,
                              void* d_out, int out_size, void* d_ws, size_t ws_size,
                              hipStream_t stream) {
    const float* x   = (const float*)d_in[0];
    const int*   idx = (const int*)d_in[1];
    const float* U   = (const float*)d_in[2];
    const float* V   = (const float*)d_in[3];
    float* out = (float*)d_out;

    unsigned short* Ut = (unsigned short*)d_ws;                 // [K_SUB][D_MODEL] bf16
    unsigned short* Vt = Ut + (size_t)K_SUB * D_MODEL;          // [D_MODEL][K_SUB] bf16
    unsigned short* P  = Vt + (size_t)K_SUB * D_MODEL;          // [N_TOK][K_SUB]  bf16
    unsigned short* xb = (unsigned short*)d_out;                // [N_TOK][D_MODEL] bf16 (temp)

    convert_x_kernel<<<(N_TOK * D_MODEL) / (256 * 8), 256, 0, stream>>>(x, xb);
    gather_u_t<<<(K_SUB / 64) * (D_MODEL / 64), 256, 0, stream>>>(U, idx, Ut);
    gather_v_t<<<(K_SUB / 64) * (D_MODEL / 64), 256, 0, stream>>>(V, idx, Vt);

    gemm1_8p<<<256, 512, 0, stream>>>(xb, Ut, P);
    gemm2_8p<<<512, 512, 0, stream>>>(P, Vt, out);
}